// Round 7
// baseline (184.691 us; speedup 1.0000x reference)
//
#include <hip/hip_runtime.h>
#include <stdint.h>

namespace {

constexpr int kB = 8;
constexpr int kCH = 256;
constexpr int kN = 2048;
constexpr int NSPLIT = 4;
constexpr int SLICE = kN / NSPLIT;   // 512 KV positions per block
constexpr int KVC = 64;              // chunk (2 subtiles of 32)
constexpr int NCHUNK = SLICE / KVC;  // 8
constexpr int QBLK = 256;            // 8 waves x 32 q-rows

constexpr float SCALE = 0.0625f;  // 256^-0.5
constexpr float LOG2E = 1.4426950408889634f;
constexpr float THR = 4.0f;  // defer-rescale threshold (P bounded by e^4)

typedef _Float16 f16x8 __attribute__((ext_vector_type(8)));
typedef _Float16 f16x4 __attribute__((ext_vector_type(4)));
typedef float f32x4 __attribute__((ext_vector_type(4)));
typedef float f32x16 __attribute__((ext_vector_type(16)));
typedef unsigned int u32x4 __attribute__((ext_vector_type(4)));

__device__ __forceinline__ void gload_lds16(const void* g, void* l) {
  __builtin_amdgcn_global_load_lds(
      (const __attribute__((address_space(1))) void*)g,
      (__attribute__((address_space(3))) void*)l, 16, 0, 0);
}

// ---------------------------------------------------------------------------
// Micro-transpose pre-pass (no LDS): z<8: kt[b][n][c]=f16(k[b][c][n]);
// z>=8: vt[b][c][n]=f16(v[b][n][c]).  Reads 256B-grouped, writes 128B-grouped.
__global__ __launch_bounds__(256) void transpose_both(
    const float* __restrict__ kin, const float* __restrict__ vin,
    _Float16* __restrict__ kt, _Float16* __restrict__ vt) {
  const bool isV = blockIdx.z >= 8;
  const int b = isV ? (int)blockIdx.z - 8 : (int)blockIdx.z;
  const int R = isV ? kN : kCH, C = isV ? kCH : kN;
  const int r0 = (isV ? (int)blockIdx.x : (int)blockIdx.y) * 64;
  const int c0 = (isV ? (int)blockIdx.y : (int)blockIdx.x) * 64;
  const float* in = isV ? vin : kin;
  _Float16* out = isV ? vt : kt;
  const int t = threadIdx.x;
  const int rr = 4 * (t >> 4), cc = 4 * (t & 15);
  const float* src = in + (size_t)b * R * C + (size_t)(r0 + rr) * C + c0 + cc;
  f32x4 v0 = *(const f32x4*)(src);
  f32x4 v1 = *(const f32x4*)(src + (size_t)C);
  f32x4 v2 = *(const f32x4*)(src + 2 * (size_t)C);
  f32x4 v3 = *(const f32x4*)(src + 3 * (size_t)C);
  _Float16* ob = out + (size_t)b * R * C + r0 + rr;
#pragma unroll
  for (int j = 0; j < 4; ++j) {
    f16x4 w;
    w[0] = (_Float16)v0[j]; w[1] = (_Float16)v1[j];
    w[2] = (_Float16)v2[j]; w[3] = (_Float16)v3[j];
    *(f16x4*)(ob + (size_t)(c0 + cc + j) * R) = w;
  }
}

// ---------------------------------------------------------------------------
// Flash-attention partial, 32x32x16 MFMA, transposed-S, in-register softmax.
// Each wave: 32 q-rows. Lane owns q-col (lane&31); kv is in-lane + one
// xor-32 exchange. P->PV fragments via cvt_pkrtz + v_permlane32_swap_b32.
__global__ __launch_bounds__(512, 2) void attn_part(
    const _Float16* __restrict__ kt, const float* __restrict__ qg,
    const _Float16* __restrict__ vt, _Float16* __restrict__ pacc,
    float* __restrict__ pm, float* __restrict__ pl)
{
  __shared__ alignas(16) char KsB[2][64 * 512];   // 2x32KB swizzled [kv][chByte]
  __shared__ alignas(16) char VsB[2][256 * 128];  // 2x32KB swizzled [c][kvByte]

  const int tid = threadIdx.x;
  const int wv = tid >> 6;
  const int lane = tid & 63;
  const int lq = lane & 31;  // q-col within tile; also row index for A-frags
  const int hi = lane >> 5;  // k-half

  const int bg = blockIdx.x & 31;  // (b,g): 32 slices pinned per-XCD
  const int qt = blockIdx.x >> 5;  // 0..7
  const int b = bg >> 2, g = bg & 3;
  const int n0w = qt * QBLK + wv * 32;
  const int kvb = g * SLICE;

  const char* ktB = (const char*)(kt + (size_t)b * kN * kCH);
  const char* vtB = (const char*)(vt + (size_t)b * kCH * kN);
  const float* qb = qg + (size_t)b * kN * kCH;

  // Q fragments (B-operand): qf[kq][j] = Q[n0w+lq][16*kq + 8*hi + j]
  f16x8 qf[16];
  {
    const float* qrow = qb + (size_t)(n0w + lq) * kCH + 8 * hi;
#pragma unroll
    for (int kq = 0; kq < 16; ++kq) {
      f32x4 a = *(const f32x4*)(qrow + 16 * kq);
      f32x4 c = *(const f32x4*)(qrow + 16 * kq + 4);
      f16x8 h;
      h[0] = (_Float16)a[0]; h[1] = (_Float16)a[1];
      h[2] = (_Float16)a[2]; h[3] = (_Float16)a[3];
      h[4] = (_Float16)c[0]; h[5] = (_Float16)c[1];
      h[6] = (_Float16)c[2]; h[7] = (_Float16)c[3];
      qf[kq] = h;
    }
  }

  f32x16 acc[8];
#pragma unroll
  for (int i = 0; i < 8; ++i) {
#pragma unroll
    for (int j = 0; j < 16; ++j) acc[i][j] = 0.f;
  }
  float m_r = -1e30f, l_r = 0.f;

  auto STAGE = [&](int bf, int kv0) {
    const char* kSrc = ktB + (size_t)kv0 * 512;  // K row (kv): 512B
    const char* vSrc = vtB + (size_t)kv0 * 2;    // V row (c): stride 4096B
    char* kDst = KsB[bf];
    char* vDst = VsB[bf];
#pragma unroll
    for (int ii = 0; ii < 4; ++ii) {
      const int j = ii * 8 + wv;  // 32 x 1KB segments each
      const int L = j * 1024 + lane * 16;
      {
        const int row = L >> 9, cb = L & 511;
        gload_lds16(kSrc + (size_t)(row << 9) + (cb ^ ((row & 7) << 4)),
                    kDst + j * 1024);
      }
      {
        const int row = L >> 7, cb = L & 127;
        gload_lds16(vSrc + (size_t)row * 4096 + (cb ^ ((row & 7) << 4)),
                    vDst + j * 1024);
      }
    }
  };

  STAGE(0, kvb);
  __syncthreads();

  for (int ck = 0; ck < NCHUNK; ++ck) {
    const int cur = ck & 1;
    if (ck + 1 < NCHUNK) STAGE(cur ^ 1, kvb + (ck + 1) * KVC);  // prefetch

#pragma unroll
    for (int t = 0; t < 2; ++t) {  // two 32-kv subtiles
      // ---- QK^T (transposed): S^T[kv32][q32] = mfma(A=K, B=Q)
      f32x16 sacc;
#pragma unroll
      for (int j = 0; j < 16; ++j) sacc[j] = 0.f;
      const int krow = t * 32 + lq;
      const char* kr = KsB[cur] + krow * 512;
      const int swk = (krow & 7) << 4;
#pragma unroll
      for (int kq = 0; kq < 16; ++kq) {
        f16x8 af = *(const f16x8*)(kr + ((32 * kq + 16 * hi) ^ swk));
        sacc = __builtin_amdgcn_mfma_f32_32x32x16_f16(af, qf[kq], sacc, 0, 0, 0);
      }

      // ---- in-lane softmax (lane owns q-col; 16 kv values + partner half)
      float t8[8];
#pragma unroll
      for (int j = 0; j < 8; ++j) t8[j] = fmaxf(sacc[2 * j], sacc[2 * j + 1]);
      float t4a = fmaxf(fmaxf(t8[0], t8[1]), fmaxf(t8[2], t8[3]));
      float t4b = fmaxf(fmaxf(t8[4], t8[5]), fmaxf(t8[6], t8[7]));
      float mx = fmaxf(t4a, t4b);
      mx = fmaxf(mx, __shfl_xor(mx, 32, 64));

      bool grow = (SCALE * mx > m_r + THR);
      if (__any((int)grow)) {  // rare after first subtile (defer-rescale)
        float mn = fmaxf(m_r, SCALE * mx);
        float corr = exp2f((m_r - mn) * LOG2E);
        m_r = mn;
        l_r *= corr;
#pragma unroll
        for (int i = 0; i < 8; ++i) {
#pragma unroll
          for (int j = 0; j < 16; ++j) acc[i][j] *= corr;
        }
      }

      float p[16];
      const float kSL = SCALE * LOG2E;
      const float mb = -m_r * LOG2E;
#pragma unroll
      for (int r = 0; r < 16; ++r) p[r] = exp2f(fmaf(sacc[r], kSL, mb));
      float s8[8];
#pragma unroll
      for (int j = 0; j < 8; ++j) s8[j] = p[2 * j] + p[2 * j + 1];
      float ls = ((s8[0] + s8[1]) + (s8[2] + s8[3])) +
                 ((s8[4] + s8[5]) + (s8[6] + s8[7]));
      ls += __shfl_xor(ls, 32, 64);
      l_r += ls;

      // ---- PV: build P B-frags in-register (cvt_pkrtz + permlane32_swap)
#pragma unroll
      for (int ks = 0; ks < 2; ++ks) {
        auto x0 = __builtin_amdgcn_cvt_pkrtz(p[8 * ks + 0], p[8 * ks + 1]);
        auto x1 = __builtin_amdgcn_cvt_pkrtz(p[8 * ks + 2], p[8 * ks + 3]);
        auto x2 = __builtin_amdgcn_cvt_pkrtz(p[8 * ks + 4], p[8 * ks + 5]);
        auto x3 = __builtin_amdgcn_cvt_pkrtz(p[8 * ks + 6], p[8 * ks + 7]);
        uint32_t a0 = __builtin_bit_cast(uint32_t, x0);
        uint32_t a1 = __builtin_bit_cast(uint32_t, x1);
        uint32_t a2 = __builtin_bit_cast(uint32_t, x2);
        uint32_t a3 = __builtin_bit_cast(uint32_t, x3);
        // exchange: lo-lanes keep X0/X1 & gain partner X0/X1 in hi words;
        // hi-lanes gain partner X2/X3 in lo words & keep X2/X3.
        asm("v_permlane32_swap_b32 %0, %1" : "+v"(a0), "+v"(a2));
        asm("v_permlane32_swap_b32 %0, %1" : "+v"(a1), "+v"(a3));
        u32x4 w; w[0] = a0; w[1] = a1; w[2] = a2; w[3] = a3;
        f16x8 pf = __builtin_bit_cast(f16x8, w);

        const int vOff = 64 * t + 32 * ks + 16 * hi;
#pragma unroll
        for (int ct = 0; ct < 8; ++ct) {
          const int vrow = ct * 32 + lq;
          f16x8 vf = *(const f16x8*)(VsB[cur] + vrow * 128 +
                                     (vOff ^ ((vrow & 7) << 4)));
          acc[ct] = __builtin_amdgcn_mfma_f32_32x32x16_f16(vf, pf, acc[ct], 0, 0, 0);
        }
      }
    }
    __syncthreads();  // drains prefetch + guards buffer reuse
  }

  // ---- store partials (unnormalized O^T) + per-row m,l
  _Float16* pb = pacc + (size_t)(b * NSPLIT + g) * kCH * kN + n0w + lq;
#pragma unroll
  for (int ct = 0; ct < 8; ++ct) {
#pragma unroll
    for (int r = 0; r < 16; ++r) {
      const int c = ct * 32 + (r & 3) + 8 * (r >> 2) + 4 * hi;
      pb[(size_t)c * kN] = (_Float16)acc[ct][r];
    }
  }
  if (lane < 32) {
    const int n = n0w + lane;
    pm[((size_t)b * kN + n) * NSPLIT + g] = m_r;
    pl[((size_t)b * kN + n) * NSPLIT + g] = l_r;
  }
}

// ---------------------------------------------------------------------------
// Merge: out[b][c][n] = sum_g a_g * pacc[b][g][c][n] / L,  a_g = e^{m_g-M}.
__global__ void attn_merge(const _Float16* __restrict__ pacc,
                           const float* __restrict__ pm,
                           const float* __restrict__ pl,
                           float* __restrict__ out) {
  const int b = blockIdx.z;
  const int c = blockIdx.y * 16 + ((int)threadIdx.x >> 4);
  const int nn0 = blockIdx.x * 256 + ((int)threadIdx.x & 15) * 16;

  const float* pmB = pm + ((size_t)b * kN + nn0) * NSPLIT;
  const float* plB = pl + ((size_t)b * kN + nn0) * NSPLIT;
  float res[16];

#pragma unroll
  for (int h = 0; h < 2; ++h) {  // halves keep register pressure low
    float mv[32], lv[32];
#pragma unroll
    for (int q = 0; q < 8; ++q) {
      *(f32x4*)&mv[q * 4] = *(const f32x4*)(pmB + h * 32 + q * 4);
      *(f32x4*)&lv[q * 4] = *(const f32x4*)(plB + h * 32 + q * 4);
    }
    f16x8 d[NSPLIT];
#pragma unroll
    for (int g = 0; g < NSPLIT; ++g)
      d[g] = *(const f16x8*)(pacc + ((size_t)(b * NSPLIT + g) * kCH + c) * kN +
                             nn0 + h * 8);
#pragma unroll
    for (int j = 0; j < 8; ++j) {
      float m0 = mv[4 * j], m1 = mv[4 * j + 1], m2 = mv[4 * j + 2], m3 = mv[4 * j + 3];
      float M = fmaxf(fmaxf(m0, m1), fmaxf(m2, m3));
      float a0 = exp2f((m0 - M) * LOG2E);
      float a1 = exp2f((m1 - M) * LOG2E);
      float a2 = exp2f((m2 - M) * LOG2E);
      float a3 = exp2f((m3 - M) * LOG2E);
      float L = a0 * lv[4 * j] + a1 * lv[4 * j + 1] + a2 * lv[4 * j + 2] +
                a3 * lv[4 * j + 3];
      float v = a0 * (float)d[0][j] + a1 * (float)d[1][j] +
                a2 * (float)d[2][j] + a3 * (float)d[3][j];
      res[h * 8 + j] = v / L;
    }
  }
  float* o = out + ((size_t)b * kCH + c) * kN + nn0;
#pragma unroll
  for (int j = 0; j < 4; ++j)
    *(f32x4*)(o + j * 4) = f32x4{res[j * 4], res[j * 4 + 1], res[j * 4 + 2], res[j * 4 + 3]};
}

// ---------------------------------------------------------------------------
// Round-1 fallback (used only if ws_size is too small). Verified correct.
constexpr int QBLK_FB = 64;
constexpr int KVBLK_FB = 64;
constexpr int KS_STRIDE_FB = kCH + 8;
constexpr int VS_STRIDE_FB = KVBLK_FB + 8;

__global__ __launch_bounds__(256, 1) void attn_fwd_fb(
    const float* __restrict__ kg, const float* __restrict__ qg,
    const float* __restrict__ vg, float* __restrict__ og)
{
  __shared__ alignas(16) _Float16 Ks[KVBLK_FB][KS_STRIDE_FB];
  __shared__ alignas(16) _Float16 Vs[kCH][VS_STRIDE_FB];
  __shared__ alignas(16) _Float16 Psf[4][16][VS_STRIDE_FB];
  __shared__ float red[4][16];

  const int tid = threadIdx.x;
  const int wv = tid >> 6, lane = tid & 63, s = lane & 15, qd = lane >> 4;
  const int b = blockIdx.x & 7, qt = blockIdx.x >> 3;
  const int n0w = qt * QBLK_FB + wv * 16;
  const float* kb = kg + (size_t)b * kCH * kN;
  const float* qb = qg + (size_t)b * kN * kCH;
  const float* vb = vg + (size_t)b * kN * kCH;
  float* ob = og + (size_t)b * kCH * kN;

  f16x8 qf[8];
  {
    const float* qrow = qb + (size_t)(n0w + s) * kCH + qd * 8;
#pragma unroll
    for (int ks = 0; ks < 8; ++ks) {
      f32x4 a = *(const f32x4*)(qrow + ks * 32);
      f32x4 c = *(const f32x4*)(qrow + ks * 32 + 4);
      f16x8 h;
      h[0] = (_Float16)a[0]; h[1] = (_Float16)a[1];
      h[2] = (_Float16)a[2]; h[3] = (_Float16)a[3];
      h[4] = (_Float16)c[0]; h[5] = (_Float16)c[1];
      h[6] = (_Float16)c[2]; h[7] = (_Float16)c[3];
      qf[ks] = h;
    }
  }
  f32x4 acc[16];
#pragma unroll
  for (int i = 0; i < 16; ++i) acc[i] = f32x4{0.f, 0.f, 0.f, 0.f};
  float m_r[4] = {-1e30f, -1e30f, -1e30f, -1e30f};
  float l_r[4] = {0.f, 0.f, 0.f, 0.f};

  for (int kv0 = 0; kv0 < kN; kv0 += KVBLK_FB) {
    __syncthreads();
    {
      const int m0 = 4 * (tid >> 4), c0b = 4 * (tid & 15);
#pragma unroll
      for (int p = 0; p < 4; ++p) {
        const int c0 = c0b + 64 * p;
        const float* src = kb + (size_t)c0 * kN + kv0 + m0;
        f32x4 r0 = *(const f32x4*)(src);
        f32x4 r1 = *(const f32x4*)(src + kN);
        f32x4 r2 = *(const f32x4*)(src + 2 * kN);
        f32x4 r3 = *(const f32x4*)(src + 3 * kN);
#pragma unroll
        for (int i = 0; i < 4; ++i) {
          f16x4 w;
          w[0] = (_Float16)r0[i]; w[1] = (_Float16)r1[i];
          w[2] = (_Float16)r2[i]; w[3] = (_Float16)r3[i];
          *(f16x4*)(&Ks[m0 + i][c0]) = w;
        }
      }
    }
    {
      const int m0 = 4 * (tid & 15), c0b = 4 * (tid >> 4);
#pragma unroll
      for (int p = 0; p < 4; ++p) {
        const int c0 = c0b + 64 * p;
        const float* src = vb + (size_t)(kv0 + m0) * kCH + c0;
        f32x4 r0 = *(const f32x4*)(src);
        f32x4 r1 = *(const f32x4*)(src + kCH);
        f32x4 r2 = *(const f32x4*)(src + 2 * kCH);
        f32x4 r3 = *(const f32x4*)(src + 3 * kCH);
#pragma unroll
        for (int i = 0; i < 4; ++i) {
          f16x4 w;
          w[0] = (_Float16)r0[i]; w[1] = (_Float16)r1[i];
          w[2] = (_Float16)r2[i]; w[3] = (_Float16)r3[i];
          *(f16x4*)(&Vs[c0 + i][m0]) = w;
        }
      }
    }
    __syncthreads();

    f32x4 sacc[4];
#pragma unroll
    for (int mc = 0; mc < 4; ++mc) sacc[mc] = f32x4{0.f, 0.f, 0.f, 0.f};
#pragma unroll
    for (int mc = 0; mc < 4; ++mc) {
#pragma unroll
      for (int ks = 0; ks < 8; ++ks) {
        f16x8 bf = *(const f16x8*)(&Ks[mc * 16 + s][ks * 32 + qd * 8]);
        sacc[mc] = __builtin_amdgcn_mfma_f32_16x16x32_f16(qf[ks], bf, sacc[mc], 0, 0, 0);
      }
    }
    float pmax[4];
#pragma unroll
    for (int r = 0; r < 4; ++r)
      pmax[r] = fmaxf(fmaxf(sacc[0][r], sacc[1][r]), fmaxf(sacc[2][r], sacc[3][r]));
#pragma unroll
    for (int off = 1; off < 16; off <<= 1) {
#pragma unroll
      for (int r = 0; r < 4; ++r)
        pmax[r] = fmaxf(pmax[r], __shfl_xor(pmax[r], off, 64));
    }
    float corr[4], lsum[4];
#pragma unroll
    for (int r = 0; r < 4; ++r) {
      float mn = fmaxf(m_r[r], SCALE * pmax[r]);
      corr[r] = exp2f((m_r[r] - mn) * LOG2E);
      m_r[r] = mn;
      lsum[r] = 0.f;
    }
#pragma unroll
    for (int mc = 0; mc < 4; ++mc) {
#pragma unroll
      for (int r = 0; r < 4; ++r) {
        float pvf = exp2f((SCALE * sacc[mc][r] - m_r[r]) * LOG2E);
        lsum[r] += pvf;
        Psf[wv][qd * 4 + r][mc * 16 + s] = (_Float16)pvf;
      }
    }
#pragma unroll
    for (int off = 1; off < 16; off <<= 1) {
#pragma unroll
      for (int r = 0; r < 4; ++r) lsum[r] += __shfl_xor(lsum[r], off, 64);
    }
#pragma unroll
    for (int r = 0; r < 4; ++r) l_r[r] = l_r[r] * corr[r] + lsum[r];
    if (s == 0) {
#pragma unroll
      for (int r = 0; r < 4; ++r) red[wv][qd * 4 + r] = corr[r];
    }
    asm volatile("s_waitcnt lgkmcnt(0)" ::: "memory");
    const float sc = red[wv][s];
#pragma unroll
    for (int i = 0; i < 16; ++i) acc[i] *= sc;
#pragma unroll
    for (int ms = 0; ms < 2; ++ms) {
      f16x8 pf = *(const f16x8*)(&Psf[wv][s][ms * 32 + qd * 8]);
#pragma unroll
      for (int ct = 0; ct < 16; ++ct) {
        f16x8 vf = *(const f16x8*)(&Vs[ct * 16 + s][ms * 32 + qd * 8]);
        acc[ct] = __builtin_amdgcn_mfma_f32_16x16x32_f16(vf, pf, acc[ct], 0, 0, 0);
      }
    }
  }
  if (s == 0) {
#pragma unroll
    for (int r = 0; r < 4; ++r) red[wv][qd * 4 + r] = 1.0f / l_r[r];
  }
  asm volatile("s_waitcnt lgkmcnt(0)" ::: "memory");
  const float inv = red[wv][s];
#pragma unroll
  for (int ct = 0; ct < 16; ++ct) {
#pragma unroll
    for (int r = 0; r < 4; ++r) {
      const int c = ct * 16 + qd * 4 + r;
      ob[(size_t)c * kN + n0w + s] = acc[ct][r] * inv;
    }
  }
}

constexpr size_t KT_ELEMS = (size_t)kB * kN * kCH;             // 4M f16
constexpr size_t PACC_ELEMS = (size_t)NSPLIT * kB * kCH * kN;  // 16M f16
constexpr size_t PM_ELEMS = (size_t)kB * kN * NSPLIT;          // 64K f32
constexpr size_t WS_NEED =
    (2 * KT_ELEMS + PACC_ELEMS) * sizeof(_Float16) + 2 * PM_ELEMS * sizeof(float);

}  // namespace

extern "C" void kernel_launch(void* const* d_in, const int* in_sizes, int n_in,
                              void* d_out, int out_size, void* d_ws, size_t ws_size,
                              hipStream_t stream) {
  (void)in_sizes; (void)n_in; (void)out_size;
  const float* k = (const float*)d_in[0];
  const float* q = (const float*)d_in[1];
  const float* v = (const float*)d_in[2];
  float* out = (float*)d_out;

  if (ws_size < WS_NEED) {
    hipLaunchKernelGGL(attn_fwd_fb, dim3(kB * (kN / QBLK_FB)), dim3(256), 0, stream,
                       k, q, v, out);
    return;
  }

  _Float16* kt = (_Float16*)d_ws;
  _Float16* vt = kt + KT_ELEMS;
  _Float16* pacc = vt + KT_ELEMS;
  float* pm = (float*)(pacc + PACC_ELEMS);
  float* pl = pm + PM_ELEMS;

  hipLaunchKernelGGL(transpose_both, dim3(kN / 64, kCH / 64, 16), dim3(256), 0,
                     stream, k, v, kt, vt);
  hipLaunchKernelGGL(attn_part, dim3(kB * (kN / QBLK) * NSPLIT), dim3(512), 0,
                     stream, kt, q, vt, pacc, pm, pl);
  hipLaunchKernelGGL(attn_merge, dim3(kN / 256, kCH / 16, kB), dim3(256), 0, stream,
                     pacc, pm, pl, out);
}

// Round 8
// 184.061 us; speedup vs baseline: 1.0034x; 1.0034x over previous
//
#include <hip/hip_runtime.h>
#include <stdint.h>

namespace {

constexpr int kB = 8;
constexpr int kCH = 256;
constexpr int kN = 2048;
constexpr int NSPLIT = 4;
constexpr int SLICE = kN / NSPLIT;   // 512 KV positions per block
constexpr int KVC = 64;              // chunk (2 subtiles of 32)
constexpr int NCHUNK = SLICE / KVC;  // 8
constexpr int QBLK = 256;            // 8 waves x 32 q-rows

constexpr float SCALE = 0.0625f;  // 256^-0.5
constexpr float LOG2E = 1.4426950408889634f;
constexpr float THR = 4.0f;  // defer-rescale threshold (P bounded by e^4)

typedef _Float16 f16x8 __attribute__((ext_vector_type(8)));
typedef _Float16 f16x4 __attribute__((ext_vector_type(4)));
typedef float f32x4 __attribute__((ext_vector_type(4)));
typedef float f32x16 __attribute__((ext_vector_type(16)));
typedef unsigned int u32x4 __attribute__((ext_vector_type(4)));

__device__ __forceinline__ void gload_lds16(const void* g, void* l) {
  __builtin_amdgcn_global_load_lds(
      (const __attribute__((address_space(1))) void*)g,
      (__attribute__((address_space(3))) void*)l, 16, 0, 0);
}

// ---------------------------------------------------------------------------
// Micro-transpose pre-pass (no LDS): z<8: kt[b][n][c]=f16(k[b][c][n]);
// z>=8: vt[b][c][n]=f16(v[b][n][c]).  Reads 256B-grouped, writes 128B-grouped.
__global__ __launch_bounds__(256) void transpose_both(
    const float* __restrict__ kin, const float* __restrict__ vin,
    _Float16* __restrict__ kt, _Float16* __restrict__ vt) {
  const bool isV = blockIdx.z >= 8;
  const int b = isV ? (int)blockIdx.z - 8 : (int)blockIdx.z;
  const int R = isV ? kN : kCH, C = isV ? kCH : kN;
  const int r0 = (isV ? (int)blockIdx.x : (int)blockIdx.y) * 64;
  const int c0 = (isV ? (int)blockIdx.y : (int)blockIdx.x) * 64;
  const float* in = isV ? vin : kin;
  _Float16* out = isV ? vt : kt;
  const int t = threadIdx.x;
  const int rr = 4 * (t >> 4), cc = 4 * (t & 15);
  const float* src = in + (size_t)b * R * C + (size_t)(r0 + rr) * C + c0 + cc;
  f32x4 v0 = *(const f32x4*)(src);
  f32x4 v1 = *(const f32x4*)(src + (size_t)C);
  f32x4 v2 = *(const f32x4*)(src + 2 * (size_t)C);
  f32x4 v3 = *(const f32x4*)(src + 3 * (size_t)C);
  _Float16* ob = out + (size_t)b * R * C + r0 + rr;
#pragma unroll
  for (int j = 0; j < 4; ++j) {
    f16x4 w;
    w[0] = (_Float16)v0[j]; w[1] = (_Float16)v1[j];
    w[2] = (_Float16)v2[j]; w[3] = (_Float16)v3[j];
    *(f16x4*)(ob + (size_t)(c0 + cc + j) * R) = w;
  }
}

// ---------------------------------------------------------------------------
// Flash-attention partial, 32x32x16 MFMA, transposed-S, in-register softmax.
// Each wave: 32 q-rows. Lane owns q-col (lane&31); kv is in-lane + one
// xor-32 exchange. P->PV fragments via cvt_pkrtz + v_permlane32_swap_b32.
// launch_bounds (512,1): 1 block/CU -> 256-VGPR budget, NO SPILL (R7 lesson:
// (512,2) caps at 128 VGPR and spills ~60MB of scratch traffic).
__global__ __launch_bounds__(512, 1) void attn_part(
    const _Float16* __restrict__ kt, const float* __restrict__ qg,
    const _Float16* __restrict__ vt, _Float16* __restrict__ pacc,
    float* __restrict__ pm, float* __restrict__ pl)
{
  __shared__ alignas(16) char KsB[2][64 * 512];   // 2x32KB swizzled [kv][chByte]
  __shared__ alignas(16) char VsB[2][256 * 128];  // 2x32KB swizzled [c][kvByte]

  const int tid = threadIdx.x;
  const int wv = tid >> 6;
  const int lane = tid & 63;
  const int lq = lane & 31;  // q-col within tile; also row index for A-frags
  const int hi = lane >> 5;  // k-half

  const int bg = blockIdx.x & 31;  // (b,g): 32 slices pinned per-XCD
  const int qt = blockIdx.x >> 5;  // 0..7
  const int b = bg >> 2, g = bg & 3;
  const int n0w = qt * QBLK + wv * 32;
  const int kvb = g * SLICE;

  const char* ktB = (const char*)(kt + (size_t)b * kN * kCH);
  const char* vtB = (const char*)(vt + (size_t)b * kCH * kN);
  const float* qb = qg + (size_t)b * kN * kCH;

  // Q fragments (B-operand): qf[kq][j] = Q[n0w+lq][16*kq + 8*hi + j]
  f16x8 qf[16];
  {
    const float* qrow = qb + (size_t)(n0w + lq) * kCH + 8 * hi;
#pragma unroll
    for (int kq = 0; kq < 16; ++kq) {
      f32x4 a = *(const f32x4*)(qrow + 16 * kq);
      f32x4 c = *(const f32x4*)(qrow + 16 * kq + 4);
      f16x8 h;
      h[0] = (_Float16)a[0]; h[1] = (_Float16)a[1];
      h[2] = (_Float16)a[2]; h[3] = (_Float16)a[3];
      h[4] = (_Float16)c[0]; h[5] = (_Float16)c[1];
      h[6] = (_Float16)c[2]; h[7] = (_Float16)c[3];
      qf[kq] = h;
    }
  }

  f32x16 acc[8];
#pragma unroll
  for (int i = 0; i < 8; ++i) {
#pragma unroll
    for (int j = 0; j < 16; ++j) acc[i][j] = 0.f;
  }
  float m_r = -1e30f, l_r = 0.f;

  auto STAGE = [&](int bf, int kv0) {
    const char* kSrc = ktB + (size_t)kv0 * 512;  // K row (kv): 512B
    const char* vSrc = vtB + (size_t)kv0 * 2;    // V row (c): stride 4096B
    char* kDst = KsB[bf];
    char* vDst = VsB[bf];
#pragma unroll
    for (int ii = 0; ii < 4; ++ii) {
      const int j = ii * 8 + wv;  // 32 x 1KB segments each
      const int L = j * 1024 + lane * 16;
      {
        const int row = L >> 9, cb = L & 511;
        gload_lds16(kSrc + (size_t)(row << 9) + (cb ^ ((row & 7) << 4)),
                    kDst + j * 1024);
      }
      {
        const int row = L >> 7, cb = L & 127;
        gload_lds16(vSrc + (size_t)row * 4096 + (cb ^ ((row & 7) << 4)),
                    vDst + j * 1024);
      }
    }
  };

  STAGE(0, kvb);
  __syncthreads();

  for (int ck = 0; ck < NCHUNK; ++ck) {
    const int cur = ck & 1;
    if (ck + 1 < NCHUNK) STAGE(cur ^ 1, kvb + (ck + 1) * KVC);  // prefetch

#pragma unroll
    for (int t = 0; t < 2; ++t) {  // two 32-kv subtiles
      // ---- QK^T (transposed): S^T[kv32][q32] = mfma(A=K, B=Q)
      f32x16 sacc;
#pragma unroll
      for (int j = 0; j < 16; ++j) sacc[j] = 0.f;
      const int krow = t * 32 + lq;
      const char* kr = KsB[cur] + krow * 512;
      const int swk = (krow & 7) << 4;
#pragma unroll
      for (int kq = 0; kq < 16; ++kq) {
        f16x8 af = *(const f16x8*)(kr + ((32 * kq + 16 * hi) ^ swk));
        sacc = __builtin_amdgcn_mfma_f32_32x32x16_f16(af, qf[kq], sacc, 0, 0, 0);
      }

      // ---- in-lane softmax (lane owns q-col; 16 kv values + partner half)
      float t8[8];
#pragma unroll
      for (int j = 0; j < 8; ++j) t8[j] = fmaxf(sacc[2 * j], sacc[2 * j + 1]);
      float t4a = fmaxf(fmaxf(t8[0], t8[1]), fmaxf(t8[2], t8[3]));
      float t4b = fmaxf(fmaxf(t8[4], t8[5]), fmaxf(t8[6], t8[7]));
      float mx = fmaxf(t4a, t4b);
      mx = fmaxf(mx, __shfl_xor(mx, 32, 64));

      bool grow = (SCALE * mx > m_r + THR);
      if (__any((int)grow)) {  // rare after first subtile (defer-rescale)
        float mn = fmaxf(m_r, SCALE * mx);
        float corr = exp2f((m_r - mn) * LOG2E);
        m_r = mn;
        l_r *= corr;
#pragma unroll
        for (int i = 0; i < 8; ++i) {
#pragma unroll
          for (int j = 0; j < 16; ++j) acc[i][j] *= corr;
        }
      }

      float p[16];
      const float kSL = SCALE * LOG2E;
      const float mb = -m_r * LOG2E;
#pragma unroll
      for (int r = 0; r < 16; ++r) p[r] = exp2f(fmaf(sacc[r], kSL, mb));
      float s8[8];
#pragma unroll
      for (int j = 0; j < 8; ++j) s8[j] = p[2 * j] + p[2 * j + 1];
      float ls = ((s8[0] + s8[1]) + (s8[2] + s8[3])) +
                 ((s8[4] + s8[5]) + (s8[6] + s8[7]));
      ls += __shfl_xor(ls, 32, 64);
      l_r += ls;

      // ---- PV: build P B-frags in-register (cvt_pkrtz + permlane32_swap)
#pragma unroll
      for (int ks = 0; ks < 2; ++ks) {
        auto x0 = __builtin_amdgcn_cvt_pkrtz(p[8 * ks + 0], p[8 * ks + 1]);
        auto x1 = __builtin_amdgcn_cvt_pkrtz(p[8 * ks + 2], p[8 * ks + 3]);
        auto x2 = __builtin_amdgcn_cvt_pkrtz(p[8 * ks + 4], p[8 * ks + 5]);
        auto x3 = __builtin_amdgcn_cvt_pkrtz(p[8 * ks + 6], p[8 * ks + 7]);
        uint32_t a0 = __builtin_bit_cast(uint32_t, x0);
        uint32_t a1 = __builtin_bit_cast(uint32_t, x1);
        uint32_t a2 = __builtin_bit_cast(uint32_t, x2);
        uint32_t a3 = __builtin_bit_cast(uint32_t, x3);
        // exchange: lo-lanes keep X0/X1 & gain partner X0/X1 in hi words;
        // hi-lanes gain partner X2/X3 in lo words & keep X2/X3.
        asm("v_permlane32_swap_b32 %0, %1" : "+v"(a0), "+v"(a2));
        asm("v_permlane32_swap_b32 %0, %1" : "+v"(a1), "+v"(a3));
        u32x4 w; w[0] = a0; w[1] = a1; w[2] = a2; w[3] = a3;
        f16x8 pf = __builtin_bit_cast(f16x8, w);

        const int vOff = 64 * t + 32 * ks + 16 * hi;
#pragma unroll
        for (int ct = 0; ct < 8; ++ct) {
          const int vrow = ct * 32 + lq;
          f16x8 vf = *(const f16x8*)(VsB[cur] + vrow * 128 +
                                     (vOff ^ ((vrow & 7) << 4)));
          acc[ct] = __builtin_amdgcn_mfma_f32_32x32x16_f16(vf, pf, acc[ct], 0, 0, 0);
        }
      }
    }
    __syncthreads();  // drains prefetch + guards buffer reuse
  }

  // ---- store partials (unnormalized O^T) + per-row m,l
  _Float16* pb = pacc + (size_t)(b * NSPLIT + g) * kCH * kN + n0w + lq;
#pragma unroll
  for (int ct = 0; ct < 8; ++ct) {
#pragma unroll
    for (int r = 0; r < 16; ++r) {
      const int c = ct * 32 + (r & 3) + 8 * (r >> 2) + 4 * hi;
      pb[(size_t)c * kN] = (_Float16)acc[ct][r];
    }
  }
  if (lane < 32) {
    const int n = n0w + lane;
    pm[((size_t)b * kN + n) * NSPLIT + g] = m_r;
    pl[((size_t)b * kN + n) * NSPLIT + g] = l_r;
  }
}

// ---------------------------------------------------------------------------
// Merge: out[b][c][n] = sum_g a_g * pacc[b][g][c][n] / L,  a_g = e^{m_g-M}.
__global__ void attn_merge(const _Float16* __restrict__ pacc,
                           const float* __restrict__ pm,
                           const float* __restrict__ pl,
                           float* __restrict__ out) {
  const int b = blockIdx.z;
  const int c = blockIdx.y * 16 + ((int)threadIdx.x >> 4);
  const int nn0 = blockIdx.x * 256 + ((int)threadIdx.x & 15) * 16;

  const float* pmB = pm + ((size_t)b * kN + nn0) * NSPLIT;
  const float* plB = pl + ((size_t)b * kN + nn0) * NSPLIT;
  float res[16];

#pragma unroll
  for (int h = 0; h < 2; ++h) {  // halves keep register pressure low
    float mv[32], lv[32];
#pragma unroll
    for (int q = 0; q < 8; ++q) {
      *(f32x4*)&mv[q * 4] = *(const f32x4*)(pmB + h * 32 + q * 4);
      *(f32x4*)&lv[q * 4] = *(const f32x4*)(plB + h * 32 + q * 4);
    }
    f16x8 d[NSPLIT];
#pragma unroll
    for (int g = 0; g < NSPLIT; ++g)
      d[g] = *(const f16x8*)(pacc + ((size_t)(b * NSPLIT + g) * kCH + c) * kN +
                             nn0 + h * 8);
#pragma unroll
    for (int j = 0; j < 8; ++j) {
      float m0 = mv[4 * j], m1 = mv[4 * j + 1], m2 = mv[4 * j + 2], m3 = mv[4 * j + 3];
      float M = fmaxf(fmaxf(m0, m1), fmaxf(m2, m3));
      float a0 = exp2f((m0 - M) * LOG2E);
      float a1 = exp2f((m1 - M) * LOG2E);
      float a2 = exp2f((m2 - M) * LOG2E);
      float a3 = exp2f((m3 - M) * LOG2E);
      float L = a0 * lv[4 * j] + a1 * lv[4 * j + 1] + a2 * lv[4 * j + 2] +
                a3 * lv[4 * j + 3];
      float v = a0 * (float)d[0][j] + a1 * (float)d[1][j] +
                a2 * (float)d[2][j] + a3 * (float)d[3][j];
      res[h * 8 + j] = v / L;
    }
  }
  float* o = out + ((size_t)b * kCH + c) * kN + nn0;
#pragma unroll
  for (int j = 0; j < 4; ++j)
    *(f32x4*)(o + j * 4) = f32x4{res[j * 4], res[j * 4 + 1], res[j * 4 + 2], res[j * 4 + 3]};
}

// ---------------------------------------------------------------------------
// Round-1 fallback (used only if ws_size is too small). Verified correct.
constexpr int QBLK_FB = 64;
constexpr int KVBLK_FB = 64;
constexpr int KS_STRIDE_FB = kCH + 8;
constexpr int VS_STRIDE_FB = KVBLK_FB + 8;

__global__ __launch_bounds__(256, 1) void attn_fwd_fb(
    const float* __restrict__ kg, const float* __restrict__ qg,
    const float* __restrict__ vg, float* __restrict__ og)
{
  __shared__ alignas(16) _Float16 Ks[KVBLK_FB][KS_STRIDE_FB];
  __shared__ alignas(16) _Float16 Vs[kCH][VS_STRIDE_FB];
  __shared__ alignas(16) _Float16 Psf[4][16][VS_STRIDE_FB];
  __shared__ float red[4][16];

  const int tid = threadIdx.x;
  const int wv = tid >> 6, lane = tid & 63, s = lane & 15, qd = lane >> 4;
  const int b = blockIdx.x & 7, qt = blockIdx.x >> 3;
  const int n0w = qt * QBLK_FB + wv * 16;
  const float* kb = kg + (size_t)b * kCH * kN;
  const float* qb = qg + (size_t)b * kN * kCH;
  const float* vb = vg + (size_t)b * kN * kCH;
  float* ob = og + (size_t)b * kCH * kN;

  f16x8 qf[8];
  {
    const float* qrow = qb + (size_t)(n0w + s) * kCH + qd * 8;
#pragma unroll
    for (int ks = 0; ks < 8; ++ks) {
      f32x4 a = *(const f32x4*)(qrow + ks * 32);
      f32x4 c = *(const f32x4*)(qrow + ks * 32 + 4);
      f16x8 h;
      h[0] = (_Float16)a[0]; h[1] = (_Float16)a[1];
      h[2] = (_Float16)a[2]; h[3] = (_Float16)a[3];
      h[4] = (_Float16)c[0]; h[5] = (_Float16)c[1];
      h[6] = (_Float16)c[2]; h[7] = (_Float16)c[3];
      qf[ks] = h;
    }
  }
  f32x4 acc[16];
#pragma unroll
  for (int i = 0; i < 16; ++i) acc[i] = f32x4{0.f, 0.f, 0.f, 0.f};
  float m_r[4] = {-1e30f, -1e30f, -1e30f, -1e30f};
  float l_r[4] = {0.f, 0.f, 0.f, 0.f};

  for (int kv0 = 0; kv0 < kN; kv0 += KVBLK_FB) {
    __syncthreads();
    {
      const int m0 = 4 * (tid >> 4), c0b = 4 * (tid & 15);
#pragma unroll
      for (int p = 0; p < 4; ++p) {
        const int c0 = c0b + 64 * p;
        const float* src = kb + (size_t)c0 * kN + kv0 + m0;
        f32x4 r0 = *(const f32x4*)(src);
        f32x4 r1 = *(const f32x4*)(src + kN);
        f32x4 r2 = *(const f32x4*)(src + 2 * kN);
        f32x4 r3 = *(const f32x4*)(src + 3 * kN);
#pragma unroll
        for (int i = 0; i < 4; ++i) {
          f16x4 w;
          w[0] = (_Float16)r0[i]; w[1] = (_Float16)r1[i];
          w[2] = (_Float16)r2[i]; w[3] = (_Float16)r3[i];
          *(f16x4*)(&Ks[m0 + i][c0]) = w;
        }
      }
    }
    {
      const int m0 = 4 * (tid & 15), c0b = 4 * (tid >> 4);
#pragma unroll
      for (int p = 0; p < 4; ++p) {
        const int c0 = c0b + 64 * p;
        const float* src = vb + (size_t)(kv0 + m0) * kCH + c0;
        f32x4 r0 = *(const f32x4*)(src);
        f32x4 r1 = *(const f32x4*)(src + kCH);
        f32x4 r2 = *(const f32x4*)(src + 2 * kCH);
        f32x4 r3 = *(const f32x4*)(src + 3 * kCH);
#pragma unroll
        for (int i = 0; i < 4; ++i) {
          f16x4 w;
          w[0] = (_Float16)r0[i]; w[1] = (_Float16)r1[i];
          w[2] = (_Float16)r2[i]; w[3] = (_Float16)r3[i];
          *(f16x4*)(&Vs[c0 + i][m0]) = w;
        }
      }
    }
    __syncthreads();

    f32x4 sacc[4];
#pragma unroll
    for (int mc = 0; mc < 4; ++mc) sacc[mc] = f32x4{0.f, 0.f, 0.f, 0.f};
#pragma unroll
    for (int mc = 0; mc < 4; ++mc) {
#pragma unroll
      for (int ks = 0; ks < 8; ++ks) {
        f16x8 bf = *(const f16x8*)(&Ks[mc * 16 + s][ks * 32 + qd * 8]);
        sacc[mc] = __builtin_amdgcn_mfma_f32_16x16x32_f16(qf[ks], bf, sacc[mc], 0, 0, 0);
      }
    }
    float pmax[4];
#pragma unroll
    for (int r = 0; r < 4; ++r)
      pmax[r] = fmaxf(fmaxf(sacc[0][r], sacc[1][r]), fmaxf(sacc[2][r], sacc[3][r]));
#pragma unroll
    for (int off = 1; off < 16; off <<= 1) {
#pragma unroll
      for (int r = 0; r < 4; ++r)
        pmax[r] = fmaxf(pmax[r], __shfl_xor(pmax[r], off, 64));
    }
    float corr[4], lsum[4];
#pragma unroll
    for (int r = 0; r < 4; ++r) {
      float mn = fmaxf(m_r[r], SCALE * pmax[r]);
      corr[r] = exp2f((m_r[r] - mn) * LOG2E);
      m_r[r] = mn;
      lsum[r] = 0.f;
    }
#pragma unroll
    for (int mc = 0; mc < 4; ++mc) {
#pragma unroll
      for (int r = 0; r < 4; ++r) {
        float pvf = exp2f((SCALE * sacc[mc][r] - m_r[r]) * LOG2E);
        lsum[r] += pvf;
        Psf[wv][qd * 4 + r][mc * 16 + s] = (_Float16)pvf;
      }
    }
#pragma unroll
    for (int off = 1; off < 16; off <<= 1) {
#pragma unroll
      for (int r = 0; r < 4; ++r) lsum[r] += __shfl_xor(lsum[r], off, 64);
    }
#pragma unroll
    for (int r = 0; r < 4; ++r) l_r[r] = l_r[r] * corr[r] + lsum[r];
    if (s == 0) {
#pragma unroll
      for (int r = 0; r < 4; ++r) red[wv][qd * 4 + r] = corr[r];
    }
    asm volatile("s_waitcnt lgkmcnt(0)" ::: "memory");
    const float sc = red[wv][s];
#pragma unroll
    for (int i = 0; i < 16; ++i) acc[i] *= sc;
#pragma unroll
    for (int ms = 0; ms < 2; ++ms) {
      f16x8 pf = *(const f16x8*)(&Psf[wv][s][ms * 32 + qd * 8]);
#pragma unroll
      for (int ct = 0; ct < 16; ++ct) {
        f16x8 vf = *(const f16x8*)(&Vs[ct * 16 + s][ms * 32 + qd * 8]);
        acc[ct] = __builtin_amdgcn_mfma_f32_16x16x32_f16(vf, pf, acc[ct], 0, 0, 0);
      }
    }
  }
  if (s == 0) {
#pragma unroll
    for (int r = 0; r < 4; ++r) red[wv][qd * 4 + r] = 1.0f / l_r[r];
  }
  asm volatile("s_waitcnt lgkmcnt(0)" ::: "memory");
  const float inv = red[wv][s];
#pragma unroll
  for (int ct = 0; ct < 16; ++ct) {
#pragma unroll
    for (int r = 0; r < 4; ++r) {
      const int c = ct * 16 + qd * 4 + r;
      ob[(size_t)c * kN + n0w + s] = acc[ct][r] * inv;
    }
  }
}

constexpr size_t KT_ELEMS = (size_t)kB * kN * kCH;             // 4M f16
constexpr size_t PACC_ELEMS = (size_t)NSPLIT * kB * kCH * kN;  // 16M f16
constexpr size_t PM_ELEMS = (size_t)kB * kN * NSPLIT;          // 64K f32
constexpr size_t WS_NEED =
    (2 * KT_ELEMS + PACC_ELEMS) * sizeof(_Float16) + 2 * PM_ELEMS * sizeof(float);

}  // namespace

extern "C" void kernel_launch(void* const* d_in, const int* in_sizes, int n_in,
                              void* d_out, int out_size, void* d_ws, size_t ws_size,
                              hipStream_t stream) {
  (void)in_sizes; (void)n_in; (void)out_size;
  const float* k = (const float*)d_in[0];
  const float* q = (const float*)d_in[1];
  const float* v = (const float*)d_in[2];
  float* out = (float*)d_out;

  if (ws_size < WS_NEED) {
    hipLaunchKernelGGL(attn_fwd_fb, dim3(kB * (kN / QBLK_FB)), dim3(256), 0, stream,
                       k, q, v, out);
    return;
  }

  _Float16* kt = (_Float16*)d_ws;
  _Float16* vt = kt + KT_ELEMS;
  _Float16* pacc = vt + KT_ELEMS;
  float* pm = (float*)(pacc + PACC_ELEMS);
  float* pl = pm + PM_ELEMS;

  hipLaunchKernelGGL(transpose_both, dim3(kN / 64, kCH / 64, 16), dim3(256), 0,
                     stream, k, v, kt, vt);
  hipLaunchKernelGGL(attn_part, dim3(kB * (kN / QBLK) * NSPLIT), dim3(512), 0,
                     stream, kt, q, vt, pacc, pm, pl);
  hipLaunchKernelGGL(attn_merge, dim3(kN / 256, kCH / 16, kB), dim3(256), 0, stream,
                     pacc, pm, pl, out);
}